// Round 10
// baseline (5833.490 us; speedup 1.0000x reference)
//
#include <hip/hip_runtime.h>

// Problem constants
#define B_   32
#define T_   256
#define N_   128
#define DIN_ 16
#define U_   64

// LDS (ushort): diffb [128 nodes][PD] node-major; difT [128 ch][PT] ch-major
#define PD 456
#define PT 136
#define LDS_BYTES ((N_*PD + N_*PT)*2)   // 151552 B

// Workspace (ushort elems)
#define WT0G_OFF 0
#define WT0C_OFF (128*256)
#define WT1G_OFF (WT0C_OFF + 64*256)
#define WT1C_OFF (WT1G_OFF + 128*384)
#define WT_TOTAL (WT1C_OFF + 64*384)
#define S2_OFF   WT_TOTAL                 // bf16 S2[128][128]
#define FIFO_OFF (S2_OFF + 128*128)       // h0' stream: [b][t%8] x 8192 ush (16KB)
#define FIFO_SLOT(bb,tt) (FIFO_OFF + ((bb)*8 + ((tt)&7))*8192)
#define FLG_BYTE ((FIFO_OFF + 32*8*8192)*2)  // int prod[32]; int cons[32]

typedef __attribute__((ext_vector_type(8))) short bfrag;
typedef __attribute__((ext_vector_type(4))) float ffrag;
typedef __attribute__((ext_vector_type(4))) unsigned short us4;
typedef __attribute__((ext_vector_type(2))) unsigned short us2;
typedef unsigned long long ull;

// LDS-only barrier (no vmcnt drain -> weight prefetches stay in flight)
#define SYNC() asm volatile("s_waitcnt lgkmcnt(0)\n\ts_barrier" ::: "memory")
#define MFMA16(a,b,c) __builtin_amdgcn_mfma_f32_16x16x32_bf16(a,b,c,0,0,0)

__device__ __forceinline__ unsigned short f2b(float x) {
  union { float f; unsigned u; } v; v.f = x;
  return (unsigned short)((v.u + 0x7fffu + ((v.u >> 16) & 1u)) >> 16);
}
__device__ __forceinline__ float sigm(float x) {
  float e = __expf(-x);
  return __builtin_amdgcn_rcpf(1.f + e);
}
__device__ __forceinline__ float tanh_(float x) {
  float e = __expf(2.f * x);
  return 1.f - 2.f * __builtin_amdgcn_rcpf(1.f + e);
}

// L0 gate k-map (K=256): [x dm0 16 | x dm12 32 | zero 16 | h dm0 64 | h dm12 128]
__device__ __forceinline__ float wval0(const float* w, int ncol, int co, int k) {
  if (k < 16)  return w[(k*3+0)*ncol+co] - w[(k*3+2)*ncol+co];
  if (k < 48)  { int j=k-16, c=j>>1;
                 return (j&1) ? 2.f*w[(c*3+2)*ncol+co] : w[(c*3+1)*ncol+co]; }
  if (k < 64)  return 0.f;
  if (k < 128) { int c=16+(k-64); return w[(c*3+0)*ncol+co] - w[(c*3+2)*ncol+co]; }
  { int j=k-128, c=16+(j>>1);
    return (j&1) ? 2.f*w[(c*3+2)*ncol+co] : w[(c*3+1)*ncol+co]; }
}
// L1 gate k-map (K=384): [h0' dm0 64 | h0' dm12 128 | h1 dm0 64 | h1 dm12 128]
__device__ __forceinline__ float wval1(const float* w, int ncol, int co, int k) {
  if (k < 64)  return w[(k*3+0)*ncol+co] - w[(k*3+2)*ncol+co];
  if (k < 192) { int j=k-64, c=j>>1;
                 return (j&1) ? 2.f*w[(c*3+2)*ncol+co] : w[(c*3+1)*ncol+co]; }
  if (k < 256) { int c=64+(k-192); return w[(c*3+0)*ncol+co] - w[(c*3+2)*ncol+co]; }
  { int j=k-256, c=64+(j>>1);
    return (j&1) ? 2.f*w[(c*3+2)*ncol+co] : w[(c*3+1)*ncol+co]; }
}
// cand k-orders (rh double-buffered):
// L0 cand cols: [x/zero 0-63 | rh dm12 @128-255 | rh dm0 @256-319]
__device__ __forceinline__ float wval0c(const float* w, int ncol, int co, int k) {
  if (k < 64)  return wval0(w, ncol, co, k);
  if (k < 192) return wval0(w, ncol, co, k + 64);   // rh dm12 -> h dm12 weights
  return wval0(w, ncol, co, k - 128);               // rh dm0  -> h dm0 weights
}
// L1 cand cols: [h0' 0-191 | rh dm12 @256-383 | rh dm0 @384-447]
__device__ __forceinline__ float wval1c(const float* w, int ncol, int co, int k) {
  if (k < 192) return wval1(w, ncol, co, k);
  if (k < 320) return wval1(w, ncol, co, k + 64);   // rh dm12 -> h1 dm12 weights
  return wval1(w, ncol, co, k - 128);               // rh dm0  -> h1 dm0 weights
}

__global__ void setup_wt(const float* __restrict__ w0g, const float* __restrict__ w0c,
                         const float* __restrict__ w1g, const float* __restrict__ w1c,
                         unsigned short* __restrict__ wt) {
  int i = blockIdx.x * blockDim.x + threadIdx.x;
  if (i >= WT_TOTAL) return;
  float v;
  if (i < WT0C_OFF)      { int co = i >> 8, k = i & 255;                 v = wval0 (w0g, 128, co, k); }
  else if (i < WT1G_OFF) { int j = i - WT0C_OFF; v = wval0c(w0c, 64, j >> 8, j & 255); }
  else if (i < WT1C_OFF) { int j = i - WT1G_OFF; v = wval1 (w1g, 128, j / 384, j % 384); }
  else                   { int j = i - WT1C_OFF; v = wval1c(w1c, 64, j / 384, j % 384); }
  wt[i] = f2b(v);
}

__global__ void setup_s2(const float* __restrict__ sup, unsigned short* __restrict__ s2) {
  int idx = blockIdx.x * blockDim.x + threadIdx.x;
  int i = idx >> 7, j = idx & 127;
  float acc = 0.f;
#pragma unroll 4
  for (int k = 0; k < 128; ++k) acc += sup[i*128 + k] * sup[k*128 + j];
  s2[idx] = f2b(acc);
}

__global__ void zero_flags(unsigned short* __restrict__ wt) {
  int* flg = (int*)((char*)wt + FLG_BYTE);
  if (threadIdx.x < 64) flg[threadIdx.x] = 0;
}

// Gate GEMM: 2 m-tiles x {r,u} co-tiles; contiguous K; 4-deep ring (8 bfrags).
template<int KT>
__device__ __forceinline__ void gate2(ffrag (&acc)[2][2], bfrag (&bw)[8],
    const unsigned short* __restrict__ arow0, const unsigned short* __restrict__ arow1,
    const unsigned short* __restrict__ bpr, const unsigned short* __restrict__ bpu,
    const int lq) {
#pragma unroll
  for (int ks = 0; ks < KT; ++ks) {
    const int k = ks & 3;
    bfrag a0 = *(const bfrag*)&arow0[32*ks + 8*lq];
    bfrag a1 = *(const bfrag*)&arow1[32*ks + 8*lq];
    bfrag br = bw[2*k], bu = bw[2*k+1];
    if (ks + 4 < KT) {
      bw[2*k]   = *(const bfrag*)&bpr[32*(ks+4) + 8*lq];
      bw[2*k+1] = *(const bfrag*)&bpu[32*(ks+4) + 8*lq];
    }
    acc[0][0] = MFMA16(a0, br, acc[0][0]);
    acc[1][0] = MFMA16(a1, br, acc[1][0]);
    acc[0][1] = MFMA16(a0, bu, acc[0][1]);
    acc[1][1] = MFMA16(a1, bu, acc[1][1]);
  }
}
// Cand GEMM: 2 m-tiles x 1 co-tile; A-cols via ks-offset list; 4-deep ring.
template<int KT>
__device__ __forceinline__ void cand1(ffrag (&acc)[2], bfrag (&bw)[4],
    const unsigned short* __restrict__ arow0, const unsigned short* __restrict__ arow1,
    const int (&kofs)[KT], const unsigned short* __restrict__ bpc, const int lq) {
#pragma unroll
  for (int ks = 0; ks < KT; ++ks) {
    const int k = ks & 3;
    bfrag a0 = *(const bfrag*)&arow0[kofs[ks] + 8*lq];
    bfrag a1 = *(const bfrag*)&arow1[kofs[ks] + 8*lq];
    bfrag bc = bw[k];
    if (ks + 4 < KT) bw[k] = *(const bfrag*)&bpc[32*(ks+4) + 8*lq];
    acc[0] = MFMA16(a0, bc, acc[0]);
    acc[1] = MFMA16(a1, bc, acc[1]);
  }
}

__global__ __launch_bounds__(1024, 4) void dcgru(
    const float* __restrict__ xseq, const int* __restrict__ slen,
    const float* __restrict__ sup,
    const float* __restrict__ b0g, const float* __restrict__ b0c,
    const float* __restrict__ b1g, const float* __restrict__ b1c,
    const float* __restrict__ wfc, const float* __restrict__ bfc,
    unsigned short* __restrict__ wt, float* __restrict__ out) {
  extern __shared__ unsigned short lds[];
  unsigned short* diffb = lds;
  unsigned short* difT  = lds + N_*PD;
  const int b    = blockIdx.x >> 1;
  const int eta  = blockIdx.x & 1;        // 0 = layer-0 producer, 1 = layer-1 consumer
  const int tid  = threadIdx.x;
  const int w    = tid >> 6;              // wave 0..15
  const int g    = w >> 2;                // GEMM m-quad: nodes [32g, 32g+32)
  const int c    = w & 3;                 // GEMM/GRU ch-tile: ch [16c, 16c+16)
  const int sD   = w & 7;                 // diffuse strip: nodes [16sD, 16sD+16)
  const int hD   = w >> 3;                // diffuse tile-list half
  const int ln   = tid & 15;
  const int lq   = (tid >> 4) & 3;
  const int L    = slen[b];
  int* flg  = (int*)((char*)wt + FLG_BYTE);
  int* prod = flg + b;
  int* cons = flg + 32 + b;
  const unsigned short* __restrict__ arow0 = diffb + (32*g      + ln)*PD;
  const unsigned short* __restrict__ arow1 = diffb + (32*g + 16 + ln)*PD;
  const ffrag fz = {0.f, 0.f, 0.f, 0.f};

  // S / S2 A-frags for own diffuse strip only (8 bfrags = 32 VGPR)
  bfrag Sf[4], S2f[4];
#pragma unroll
  for (int ks = 0; ks < 4; ++ks) {
    const float* pS = sup + (16*sD + ln)*N_ + 32*ks + 8*lq;
    union { bfrag v; unsigned short u[8]; } tmp;
#pragma unroll
    for (int j = 0; j < 8; ++j) tmp.u[j] = f2b(pS[j]);
    Sf[ks] = tmp.v;
    S2f[ks] = *(const bfrag*)&wt[S2_OFF + (16*sD + ln)*N_ + 32*ks + 8*lq];
  }

  // diffuse ch-tile nt for own strip: dm1=S@xc, dm2=S2@xc; cols colc + 2*ln + {0,1}
  auto diffuse = [&](int nt, int colc) {
    bfrag bf[4];
#pragma unroll
    for (int ks = 0; ks < 4; ++ks)
      bf[ks] = *(const bfrag*)&difT[(16*nt + ln)*PT + 32*ks + 8*lq];
    ffrag a1 = fz, a2 = fz;
#pragma unroll
    for (int ks = 0; ks < 4; ++ks) {
      a1 = MFMA16(Sf[ks],  bf[ks], a1);
      a2 = MFMA16(S2f[ks], bf[ks], a2);
    }
    const int n0 = 16*sD + 4*lq;
    const int col = colc + 2*ln;
#pragma unroll
    for (int r = 0; r < 4; ++r) {
      us2 pq = {f2b(a1[r]), f2b(a2[r])};
      *(us2*)&diffb[(n0 + r)*PD + col] = pq;
    }
  };
  // dump wave's 2m x 1ch C-frags into both layouts
  auto dumpCell = [&](ffrag (&v)[2], int colBase, int rowBase) {
    const int chh = 16*c + ln;
#pragma unroll
    for (int i = 0; i < 2; ++i) {
      const int n0 = 32*g + 16*i + 4*lq;
      unsigned short sv[4];
#pragma unroll
      for (int r = 0; r < 4; ++r) sv[r] = f2b(v[i][r]);
#pragma unroll
      for (int r = 0; r < 4; ++r) diffb[(n0 + r)*PD + colBase + chh] = sv[r];
      us4 q = {sv[0], sv[1], sv[2], sv[3]};
      *(us4*)&difT[(rowBase + chh)*PT + n0] = q;
    }
  };
  auto prebG = [&](bfrag (&bw)[8], const unsigned short* bpr, const unsigned short* bpu) {
#pragma unroll
    for (int k = 0; k < 4; ++k) {
      bw[2*k]   = *(const bfrag*)&bpr[32*k + 8*lq];
      bw[2*k+1] = *(const bfrag*)&bpu[32*k + 8*lq];
    }
  };
  auto prebC = [&](bfrag (&bw)[4], const unsigned short* bpc) {
#pragma unroll
    for (int k = 0; k < 4; ++k) bw[k] = *(const bfrag*)&bpc[32*k + 8*lq];
  };
  auto waitge = [&](int* p, int seq) {
    if ((tid & 63) == 0) {
      int it = 0;
      while (__hip_atomic_load(p, __ATOMIC_RELAXED, __HIP_MEMORY_SCOPE_AGENT) < seq) {
        __builtin_amdgcn_s_sleep(1);
        if (++it > (1 << 24)) break;            // failsafe: never hard-hang
      }
    }
  };

  bfrag bw8[8];
  bfrag bw4[4];

  if (eta == 0) {
    // ===== Block A: L0. cols [x 0-15|x dm12 16-47|z 48-63|h dm0 64-127|h dm12 128-255|rh dm0 256-319]
    const unsigned short* bpr = wt + WT0G_OFF + (16*c      + ln)*256;
    const unsigned short* bpu = wt + WT0G_OFF + (16*(4+c)  + ln)*256;
    const unsigned short* bpc = wt + WT0C_OFF + (16*c      + ln)*256;
    const float bgr = b0g[16*c + ln], bgu = b0g[64 + 16*c + ln];
    const float bcv = b0c[16*c + ln];
    const int kofs0[8] = {0, 32, 128, 160, 192, 224, 256, 288};
    ffrag h0m[2] = {fz, fz};

    for (int i = tid; i < N_*16; i += 1024)    // zero pad cols [48,64) once
      diffb[(i >> 4)*PD + 48 + (i & 15)] = 0;
    float2 xv = *(const float2*)&xseq[(size_t)(b*T_)*N_*DIN_ + 2*tid];

#pragma clang loop unroll(disable)
    for (int t = 0; t < L; ++t) {
      { // P1: stage x (cols 0-15 / difT rows 0-15); dump h0 (cols 64-127 / rows 16-79)
        const int node = tid >> 3, cc = 2*(tid & 7);
        unsigned short s0 = f2b(xv.x), s1 = f2b(xv.y);
        us2 q = {s0, s1};
        *(us2*)&diffb[node*PD + cc] = q;
        difT[(cc+0)*PT + node] = s0; difT[(cc+1)*PT + node] = s1;
        dumpCell(h0m, 64, 16);
        int tn = t + 1 < L ? t + 1 : L - 1;
        xv = *(const float2*)&xseq[(size_t)(b*T_ + tn)*N_*DIN_ + 2*tid];
        prebG(bw8, bpr, bpu);
      }
      SYNC();                                            // BAR1
      if (hD == 0) { diffuse(0, 16);  diffuse(1, 128); diffuse(2, 160); }
      else         { diffuse(3, 192); diffuse(4, 224); }
      SYNC();                                            // BAR2
      ffrag u0s[2], rh[2];
      {
        ffrag ga[2][2] = {{fz, fz}, {fz, fz}};
        gate2<8>(ga, bw8, arow0, arow1, bpr, bpu, lq);
#pragma unroll
        for (int i = 0; i < 2; ++i)
#pragma unroll
          for (int r = 0; r < 4; ++r) {
            float rr = sigm(ga[i][0][r] + bgr);
            rh[i][r]  = rr * h0m[i][r];
            u0s[i][r] = sigm(ga[i][1][r] + bgu);
          }
      }
      dumpCell(rh, 256, 16);    // rh dm0 -> fresh cols; difT rows 16-79 safe post-BAR2
      prebC(bw4, bpc);
      SYNC();                                            // BAR3
      if (hD == 0) { diffuse(1, 128); diffuse(2, 160); } // rh dm12 overwrite
      else         { diffuse(3, 192); diffuse(4, 224); }
      SYNC();                                            // BAR4
      {
        ffrag ca[2] = {fz, fz};
        cand1<8>(ca, bw4, arow0, arow1, kofs0, bpc, lq);
#pragma unroll
        for (int i = 0; i < 2; ++i)
#pragma unroll
          for (int r = 0; r < 4; ++r) {
            float cc = tanh_(ca[i][r] + bcv);
            float uu = u0s[i][r];
            h0m[i][r] = uu*h0m[i][r] + (1.f - uu)*cc;
          }
      }
      if (t >= 8) waitge(cons, t - 7);                   // FIFO backpressure
      { // send h0' ch-major [64 ch][128 nodes]
        unsigned short* slot = wt + FIFO_SLOT(b, t);
        const int chh = 16*c + ln;
#pragma unroll
        for (int i = 0; i < 2; ++i) {
          const int n0 = 32*g + 16*i + 4*lq;
          us4 q = {f2b(h0m[i][0]), f2b(h0m[i][1]), f2b(h0m[i][2]), f2b(h0m[i][3])};
          *(us4*)&slot[chh*128 + n0] = q;
        }
      }
      __syncthreads();   // BAR5: drains sends (vmcnt) + protects LDS for next P1
      if (tid == 0)
        __hip_atomic_fetch_add(prod, 1, __ATOMIC_RELEASE, __HIP_MEMORY_SCOPE_AGENT);
    }
    return;
  }

  // ===== Block B: L1. cols [h0' dm0 0-63|h0' dm12 64-191|h1 dm0 192-255|h1/rh dm12 256-383|rh dm0 384-447]
  {
    const unsigned short* bpr = wt + WT1G_OFF + (16*c     + ln)*384;
    const unsigned short* bpu = wt + WT1G_OFF + (16*(4+c) + ln)*384;
    const unsigned short* bpc = wt + WT1C_OFF + (16*c     + ln)*384;
    const float bgr = b1g[16*c + ln], bgu = b1g[64 + 16*c + ln];
    const float bcv = b1c[16*c + ln];
    const int kofs1[12] = {0, 32, 64, 96, 128, 160, 256, 288, 320, 352, 384, 416};
    ffrag h1m[2] = {fz, fz};

#pragma clang loop unroll(disable)
    for (int t = 0; t < L; ++t) {
      waitge(prod, t + 1);
      { // P1: recv h0'(t) -> difT rows 0-63 + diffb cols 0-63; dump h1 (192 / 64)
        const unsigned short* slot = wt + FIFO_SLOT(b, t);
#pragma unroll
        for (int rep = 0; rep < 2; ++rep) {
          const int idx = tid + 1024*rep;            // u64 index in 16KB slot
          const int ch = idx >> 5, n0 = (idx & 31)*4;
          ull v = __hip_atomic_load((const ull*)&slot[ch*128 + n0],
                                    __ATOMIC_RELAXED, __HIP_MEMORY_SCOPE_AGENT);
          *(ull*)&difT[ch*PT + n0] = v;
          union { ull u; unsigned short s[4]; } cv; cv.u = v;
#pragma unroll
          for (int j = 0; j < 4; ++j) diffb[(n0 + j)*PD + ch] = cv.s[j];
        }
        dumpCell(h1m, 192, 64);
        prebG(bw8, bpr, bpu);
      }
      SYNC();                                            // BAR1
      if (tid == 0)
        __hip_atomic_fetch_add(cons, 1, __ATOMIC_RELEASE, __HIP_MEMORY_SCOPE_AGENT);
      { // diffuse1: 8 tiles x 8 strips over 16 waves (4 tiles each, own strip)
        const int t0 = 4*hD;
        diffuse(t0, 64 + 192*hD);  diffuse(t0+1, 96 + 192*hD);
        diffuse(t0+2, 128 + 192*hD); diffuse(t0+3, 160 + 192*hD);
      }
      SYNC();                                            // BAR2
      ffrag u1s[2], rh[2];
      {
        ffrag ga[2][2] = {{fz, fz}, {fz, fz}};
        gate2<12>(ga, bw8, arow0, arow1, bpr, bpu, lq);
#pragma unroll
        for (int i = 0; i < 2; ++i)
#pragma unroll
          for (int r = 0; r < 4; ++r) {
            float rr = sigm(ga[i][0][r] + bgr);
            rh[i][r]  = rr * h1m[i][r];
            u1s[i][r] = sigm(ga[i][1][r] + bgu);
          }
      }
      dumpCell(rh, 384, 64);    // rh dm0 -> fresh cols; difT rows 64-127 safe post-BAR2
      prebC(bw4, bpc);
      SYNC();                                            // BAR3
      { // diffuse2: rh tiles 4-7, 2 per wave
        const int t0 = 4 + 2*hD;
        diffuse(t0, 256 + 64*hD); diffuse(t0+1, 288 + 64*hD);
      }
      SYNC();                                            // BAR4
      {
        ffrag ca[2] = {fz, fz};
        cand1<12>(ca, bw4, arow0, arow1, kofs1, bpc, lq);
#pragma unroll
        for (int i = 0; i < 2; ++i)
#pragma unroll
          for (int r = 0; r < 4; ++r) {
            float cc = tanh_(ca[i][r] + bcv);
            float uu = u1s[i][r];
            h1m[i][r] = uu*h1m[i][r] + (1.f - uu)*cc;
          }
      }
      SYNC();                                            // BAR5 (cand reads done)
    }

    // Head: relu(h1) @ W_fc + b_fc, max over nodes
    {
      float* hb = (float*)lds;                  // [128][64]
#pragma unroll
      for (int i = 0; i < 2; ++i)
#pragma unroll
        for (int r = 0; r < 4; ++r) {
          float v = h1m[i][r];
          hb[(32*g + 16*i + 4*lq + r)*U_ + 16*c + ln] = v > 0.f ? v : 0.f;
        }
    }
    __syncthreads();
    float* hb = (float*)lds;
    float* lb = hb + N_*U_;
    if (tid < N_) {
      float lg[4];
#pragma unroll
      for (int j = 0; j < 4; ++j) lg[j] = bfc[j];
      for (int ch = 0; ch < U_; ++ch) {
        float v = hb[tid*U_ + ch];
#pragma unroll
        for (int j = 0; j < 4; ++j) lg[j] += v * wfc[ch*4 + j];
      }
#pragma unroll
      for (int j = 0; j < 4; ++j) lb[tid*4 + j] = lg[j];
    }
    __syncthreads();
    if (tid < 4) {
      float m = lb[tid];
      for (int n = 1; n < N_; ++n) m = fmaxf(m, lb[n*4 + tid]);
      out[b*4 + tid] = m;
    }
  }
}

extern "C" void kernel_launch(void* const* d_in, const int* in_sizes, int n_in,
                              void* d_out, int out_size, void* d_ws, size_t ws_size,
                              hipStream_t stream) {
  const float* xseq = (const float*)d_in[0];
  const int*   slen = (const int*)  d_in[1];
  const float* sup  = (const float*)d_in[2];
  const float* w0g  = (const float*)d_in[3];
  const float* b0g  = (const float*)d_in[4];
  const float* w0c  = (const float*)d_in[5];
  const float* b0c  = (const float*)d_in[6];
  const float* w1g  = (const float*)d_in[7];
  const float* b1g  = (const float*)d_in[8];
  const float* w1c  = (const float*)d_in[9];
  const float* b1c  = (const float*)d_in[10];
  const float* wfc  = (const float*)d_in[11];
  const float* bfc  = (const float*)d_in[12];
  float* out = (float*)d_out;
  unsigned short* wt = (unsigned short*)d_ws;

  (void)hipFuncSetAttribute((const void*)dcgru,
                            hipFuncAttributeMaxDynamicSharedMemorySize, LDS_BYTES);
  zero_flags<<<dim3(1), dim3(64), 0, stream>>>(wt);
  setup_wt<<<dim3((WT_TOTAL + 255)/256), dim3(256), 0, stream>>>(w0g, w0c, w1g, w1c, wt);
  setup_s2<<<dim3(64), dim3(256), 0, stream>>>(sup, wt + S2_OFF);
  dcgru<<<dim3(64), dim3(1024), LDS_BYTES, stream>>>(
      xseq, slen, sup, b0g, b0c, b1g, b1c, wfc, bfc, wt, out);
}

// Round 11
// 4978.792 us; speedup vs baseline: 1.1717x; 1.1717x over previous
//
#include <hip/hip_runtime.h>

// Problem constants
#define B_   32
#define T_   256
#define N_   128
#define DIN_ 16
#define U_   64

// LDS (ushort): diffb [128 nodes][PD] node-major; difT [128 ch][PT] ch-major
#define PD 456
#define PT 136
#define LDS_BYTES ((N_*PD + N_*PT)*2)   // 151552 B

// Workspace (ushort elems)
#define WT0G_OFF 0
#define WT0C_OFF (128*256)
#define WT1G_OFF (WT0C_OFF + 64*256)
#define WT1C_OFF (WT1G_OFF + 128*384)
#define WT_TOTAL (WT1C_OFF + 64*384)
#define S2_OFF   WT_TOTAL                 // bf16 S2[128][128]
#define FIFO_OFF (S2_OFF + 128*128)       // h0' stream: [b][t%8] x 8192 ush (16KB)
#define FIFO_SLOT(bb,tt) (FIFO_OFF + ((bb)*8 + ((tt)&7))*8192)
#define FLG_BYTE ((FIFO_OFF + 32*8*8192)*2)  // int prod[32]; int cons[32]

typedef __attribute__((ext_vector_type(8))) short bfrag;
typedef __attribute__((ext_vector_type(4))) float ffrag;
typedef __attribute__((ext_vector_type(4))) unsigned short us4;
typedef __attribute__((ext_vector_type(2))) unsigned short us2;
typedef unsigned long long ull;

// LDS-only barrier (no vmcnt drain -> weight/FIFO prefetches stay in flight)
#define SYNC() asm volatile("s_waitcnt lgkmcnt(0)\n\ts_barrier" ::: "memory")
#define MFMA16(a,b,c) __builtin_amdgcn_mfma_f32_16x16x32_bf16(a,b,c,0,0,0)

__device__ __forceinline__ unsigned short f2b(float x) {
  union { float f; unsigned u; } v; v.f = x;
  return (unsigned short)((v.u + 0x7fffu + ((v.u >> 16) & 1u)) >> 16);
}
__device__ __forceinline__ float sigm(float x) {
  float e = __expf(-x);
  return __builtin_amdgcn_rcpf(1.f + e);
}
__device__ __forceinline__ float tanh_(float x) {
  float e = __expf(2.f * x);
  return 1.f - 2.f * __builtin_amdgcn_rcpf(1.f + e);
}

// L0 gate k-map (K=256): [x dm0 16 | x dm12 32 | zero 16 | h dm0 64 | h dm12 128]
__device__ __forceinline__ float wval0(const float* w, int ncol, int co, int k) {
  if (k < 16)  return w[(k*3+0)*ncol+co] - w[(k*3+2)*ncol+co];
  if (k < 48)  { int j=k-16, c=j>>1;
                 return (j&1) ? 2.f*w[(c*3+2)*ncol+co] : w[(c*3+1)*ncol+co]; }
  if (k < 64)  return 0.f;
  if (k < 128) { int c=16+(k-64); return w[(c*3+0)*ncol+co] - w[(c*3+2)*ncol+co]; }
  { int j=k-128, c=16+(j>>1);
    return (j&1) ? 2.f*w[(c*3+2)*ncol+co] : w[(c*3+1)*ncol+co]; }
}
// L1 gate k-map (K=384): [h0' dm0 64 | h0' dm12 128 | h1 dm0 64 | h1 dm12 128]
__device__ __forceinline__ float wval1(const float* w, int ncol, int co, int k) {
  if (k < 64)  return w[(k*3+0)*ncol+co] - w[(k*3+2)*ncol+co];
  if (k < 192) { int j=k-64, c=j>>1;
                 return (j&1) ? 2.f*w[(c*3+2)*ncol+co] : w[(c*3+1)*ncol+co]; }
  if (k < 256) { int c=64+(k-192); return w[(c*3+0)*ncol+co] - w[(c*3+2)*ncol+co]; }
  { int j=k-256, c=64+(j>>1);
    return (j&1) ? 2.f*w[(c*3+2)*ncol+co] : w[(c*3+1)*ncol+co]; }
}
// cand k-orders (rh double-buffered):
// L0 cand cols: [x/zero 0-63 | rh dm12 @128-255 | rh dm0 @256-319]
__device__ __forceinline__ float wval0c(const float* w, int ncol, int co, int k) {
  if (k < 64)  return wval0(w, ncol, co, k);
  if (k < 192) return wval0(w, ncol, co, k + 64);   // rh dm12 -> h dm12 weights
  return wval0(w, ncol, co, k - 128);               // rh dm0  -> h dm0 weights
}
// L1 cand cols: [h0' 0-191 | rh dm12 @256-383 | rh dm0 @384-447]
__device__ __forceinline__ float wval1c(const float* w, int ncol, int co, int k) {
  if (k < 192) return wval1(w, ncol, co, k);
  if (k < 320) return wval1(w, ncol, co, k + 64);   // rh dm12 -> h1 dm12 weights
  return wval1(w, ncol, co, k - 128);               // rh dm0  -> h1 dm0 weights
}

__global__ void setup_wt(const float* __restrict__ w0g, const float* __restrict__ w0c,
                         const float* __restrict__ w1g, const float* __restrict__ w1c,
                         unsigned short* __restrict__ wt) {
  int i = blockIdx.x * blockDim.x + threadIdx.x;
  if (i >= WT_TOTAL) return;
  float v;
  if (i < WT0C_OFF)      { int co = i >> 8, k = i & 255;                 v = wval0 (w0g, 128, co, k); }
  else if (i < WT1G_OFF) { int j = i - WT0C_OFF; v = wval0c(w0c, 64, j >> 8, j & 255); }
  else if (i < WT1C_OFF) { int j = i - WT1G_OFF; v = wval1 (w1g, 128, j / 384, j % 384); }
  else                   { int j = i - WT1C_OFF; v = wval1c(w1c, 64, j / 384, j % 384); }
  wt[i] = f2b(v);
}

__global__ void setup_s2(const float* __restrict__ sup, unsigned short* __restrict__ s2) {
  int idx = blockIdx.x * blockDim.x + threadIdx.x;
  int i = idx >> 7, j = idx & 127;
  float acc = 0.f;
#pragma unroll 4
  for (int k = 0; k < 128; ++k) acc += sup[i*128 + k] * sup[k*128 + j];
  s2[idx] = f2b(acc);
}

__global__ void zero_flags(unsigned short* __restrict__ wt) {
  int* flg = (int*)((char*)wt + FLG_BYTE);
  if (threadIdx.x < 64) flg[threadIdx.x] = 0;
}

// Gate GEMM: 2 m-tiles x 4 co-tiles; contiguous K; 4-deep rolling ring (16 bfrags).
template<int KT>
__device__ __forceinline__ void gate4(ffrag (&acc)[2][4], bfrag (&bw)[16],
    const unsigned short* __restrict__ arow0, const unsigned short* __restrict__ arow1,
    const unsigned short* const (&bp)[4], const int lq) {
#pragma unroll
  for (int ks = 0; ks < KT; ++ks) {
    const int k = ks & 3;
    bfrag a0 = *(const bfrag*)&arow0[32*ks + 8*lq];
    bfrag a1 = *(const bfrag*)&arow1[32*ks + 8*lq];
    bfrag bb0 = bw[4*k], bb1 = bw[4*k+1], bb2 = bw[4*k+2], bb3 = bw[4*k+3];
    if (ks + 4 < KT) {
#pragma unroll
      for (int n = 0; n < 4; ++n)
        bw[4*k+n] = *(const bfrag*)&bp[n][32*(ks+4) + 8*lq];
    }
    acc[0][0] = MFMA16(a0, bb0, acc[0][0]);
    acc[1][0] = MFMA16(a1, bb0, acc[1][0]);
    acc[0][1] = MFMA16(a0, bb1, acc[0][1]);
    acc[1][1] = MFMA16(a1, bb1, acc[1][1]);
    acc[0][2] = MFMA16(a0, bb2, acc[0][2]);
    acc[1][2] = MFMA16(a1, bb2, acc[1][2]);
    acc[0][3] = MFMA16(a0, bb3, acc[0][3]);
    acc[1][3] = MFMA16(a1, bb3, acc[1][3]);
  }
}
// Cand GEMM: 2 m-tiles x 2 co-tiles; A-cols via ks-offset list (weights contiguous).
template<int KT>
__device__ __forceinline__ void cand2(ffrag (&acc)[2][2], bfrag (&bw)[8],
    const unsigned short* __restrict__ arow0, const unsigned short* __restrict__ arow1,
    const int (&kofs)[KT], const unsigned short* const (&bp)[2], const int lq) {
#pragma unroll
  for (int ks = 0; ks < KT; ++ks) {
    const int k = ks & 3;
    bfrag a0 = *(const bfrag*)&arow0[kofs[ks] + 8*lq];
    bfrag a1 = *(const bfrag*)&arow1[kofs[ks] + 8*lq];
    bfrag bb0 = bw[2*k], bb1 = bw[2*k+1];
    if (ks + 4 < KT) {
      bw[2*k]   = *(const bfrag*)&bp[0][32*(ks+4) + 8*lq];
      bw[2*k+1] = *(const bfrag*)&bp[1][32*(ks+4) + 8*lq];
    }
    acc[0][0] = MFMA16(a0, bb0, acc[0][0]);
    acc[1][0] = MFMA16(a1, bb0, acc[1][0]);
    acc[0][1] = MFMA16(a0, bb1, acc[0][1]);
    acc[1][1] = MFMA16(a1, bb1, acc[1][1]);
  }
}

__global__ __launch_bounds__(512, 2) void dcgru(
    const float* __restrict__ xseq, const int* __restrict__ slen,
    const float* __restrict__ sup,
    const float* __restrict__ b0g, const float* __restrict__ b0c,
    const float* __restrict__ b1g, const float* __restrict__ b1c,
    const float* __restrict__ wfc, const float* __restrict__ bfc,
    unsigned short* __restrict__ wt, float* __restrict__ out) {
  extern __shared__ unsigned short lds[];
  unsigned short* diffb = lds;
  unsigned short* difT  = lds + N_*PD;
  // XCD-local pairing: round-robin dispatch puts blockIdx%8 on XCD (blockIdx%8).
  // A = x (bit3=0) and B = x+8 (bit3=1) share low-3 bits -> same XCD -> FIFO and
  // flags stay in one L2 instead of crossing the fabric.
  const int b    = (blockIdx.x & 7) | ((blockIdx.x >> 4) << 3);
  const int eta  = (blockIdx.x >> 3) & 1;   // 0 = layer-0 producer, 1 = layer-1 consumer
  const int tid  = threadIdx.x;
  const int w    = tid >> 6;              // wave 0..7
  const int g    = w >> 1;                // node quad: nodes [32g, 32g+32)
  const int e    = w & 1;                 // tile-list half / ch half
  const int ln   = tid & 15;
  const int lq   = (tid >> 4) & 3;
  const int L    = slen[b];
  int* flg  = (int*)((char*)wt + FLG_BYTE);
  int* prod = flg + b;
  int* cons = flg + 32 + b;
  const unsigned short* __restrict__ arow0 = diffb + (32*g      + ln)*PD;
  const unsigned short* __restrict__ arow1 = diffb + (32*g + 16 + ln)*PD;
  const ffrag fz = {0.f, 0.f, 0.f, 0.f};

  // S / S2 A-frags for BOTH strips of this wave's node quad (16 bfrags);
  // one difT read feeds 2 strips' MFMAs.
  bfrag Sf[2][4], S2f[2][4];
#pragma unroll
  for (int si = 0; si < 2; ++si)
#pragma unroll
    for (int ks = 0; ks < 4; ++ks) {
      const float* pS = sup + (32*g + 16*si + ln)*N_ + 32*ks + 8*lq;
      union { bfrag v; unsigned short u[8]; } tmp;
#pragma unroll
      for (int j = 0; j < 8; ++j) tmp.u[j] = f2b(pS[j]);
      Sf[si][ks] = tmp.v;
      S2f[si][ks] = *(const bfrag*)&wt[S2_OFF + (32*g + 16*si + ln)*N_ + 32*ks + 8*lq];
    }

  // dm1=S@xc, dm2=S2@xc for ch-tile t (2 strips); interleaved cols colc + 2*ln + {0,1}
  auto diffuse = [&](int t, int colc) {
    bfrag bf[4];
#pragma unroll
    for (int ks = 0; ks < 4; ++ks)
      bf[ks] = *(const bfrag*)&difT[(16*t + ln)*PT + 32*ks + 8*lq];
#pragma unroll
    for (int si = 0; si < 2; ++si) {
      ffrag a1 = fz, a2 = fz;
#pragma unroll
      for (int ks = 0; ks < 4; ++ks) {
        a1 = MFMA16(Sf[si][ks],  bf[ks], a1);
        a2 = MFMA16(S2f[si][ks], bf[ks], a2);
      }
      const int n0 = 32*g + 16*si + 4*lq;
      const int col = colc + 2*ln;
#pragma unroll
      for (int r = 0; r < 4; ++r) {
        us2 pq = {f2b(a1[r]), f2b(a2[r])};
        *(us2*)&diffb[(n0 + r)*PD + col] = pq;
      }
    }
  };
  // dump wave's 2m x 2ch C-frags into both layouts (ch-half e)
  auto dumpCell = [&](ffrag (&v)[2][2], int colBase, int rowBase) {
#pragma unroll
    for (int i = 0; i < 2; ++i)
#pragma unroll
      for (int j = 0; j < 2; ++j) {
        const int chh = 32*e + 16*j + ln;
        const int n0 = 32*g + 16*i + 4*lq;
        unsigned short sv[4];
#pragma unroll
        for (int r = 0; r < 4; ++r) sv[r] = f2b(v[i][j][r]);
#pragma unroll
        for (int r = 0; r < 4; ++r) diffb[(n0 + r)*PD + colBase + chh] = sv[r];
        us4 q = {sv[0], sv[1], sv[2], sv[3]};
        *(us4*)&difT[(rowBase + chh)*PT + n0] = q;
      }
  };
  auto prebG16 = [&](bfrag (&bw)[16], const unsigned short* const (&bp)[4]) {
#pragma unroll
    for (int k = 0; k < 4; ++k)
#pragma unroll
      for (int n = 0; n < 4; ++n)
        bw[4*k+n] = *(const bfrag*)&bp[n][32*k + 8*lq];
  };
  auto prebC8 = [&](bfrag (&bw)[8], const unsigned short* const (&bp)[2]) {
#pragma unroll
    for (int k = 0; k < 4; ++k) {
      bw[2*k]   = *(const bfrag*)&bp[0][32*k + 8*lq];
      bw[2*k+1] = *(const bfrag*)&bp[1][32*k + 8*lq];
    }
  };
  auto waitge = [&](int* p, int seq) {
    if ((tid & 63) == 0) {
      int it = 0;
      while (__hip_atomic_load(p, __ATOMIC_RELAXED, __HIP_MEMORY_SCOPE_AGENT) < seq) {
        __builtin_amdgcn_s_sleep(1);
        if (++it > (1 << 24)) break;            // failsafe: never hard-hang
      }
    }
  };

  bfrag bw16[16];
  bfrag bw8[8];

  if (eta == 0) {
    // ===== Block A: L0. cols [x 0-15|x dm12 16-47|z 48-63|h dm0 64-127|h dm12 128-255|rh dm0 256-319]
    const unsigned short* bpg[4] = {
      wt + WT0G_OFF + (16*(2*e)     + ln)*256, wt + WT0G_OFF + (16*(2*e + 1) + ln)*256,
      wt + WT0G_OFF + (16*(4 + 2*e) + ln)*256, wt + WT0G_OFF + (16*(5 + 2*e) + ln)*256 };
    const unsigned short* bpc[2] = {
      wt + WT0C_OFF + (16*(2*e) + ln)*256, wt + WT0C_OFF + (16*(2*e + 1) + ln)*256 };
    const float bgr[2] = { b0g[32*e + ln], b0g[32*e + 16 + ln] };
    const float bgu[2] = { b0g[64 + 32*e + ln], b0g[64 + 32*e + 16 + ln] };
    const float bcv[2] = { b0c[32*e + ln], b0c[32*e + 16 + ln] };
    const int kofs0[8] = {0, 32, 128, 160, 192, 224, 256, 288};
    ffrag h0m[2][2] = {{fz, fz}, {fz, fz}};

    for (int i = tid; i < N_*16; i += 512)     // zero pad cols [48,64) once
      diffb[(i >> 4)*PD + 48 + (i & 15)] = 0;
    float4 xv = *(const float4*)&xseq[(size_t)(b*T_)*N_*DIN_ + 4*tid];

#pragma clang loop unroll(disable)
    for (int t = 0; t < L; ++t) {
      { // P1: stage x (cols 0-15 / difT rows 0-15); dump h0 (cols 64-127 / rows 16-79)
        const int node = tid >> 2, c = 4*(tid & 3);
        unsigned short s0 = f2b(xv.x), s1 = f2b(xv.y), s2 = f2b(xv.z), s3 = f2b(xv.w);
        us4 q = {s0, s1, s2, s3};
        *(us4*)&diffb[node*PD + c] = q;
        difT[(c+0)*PT + node] = s0; difT[(c+1)*PT + node] = s1;
        difT[(c+2)*PT + node] = s2; difT[(c+3)*PT + node] = s3;
        dumpCell(h0m, 64, 16);
        int tn = t + 1 < L ? t + 1 : L - 1;
        xv = *(const float4*)&xseq[(size_t)(b*T_ + tn)*N_*DIN_ + 4*tid];
        prebG16(bw16, bpg);
      }
      SYNC();                                            // BAR1
      if (e == 0) { diffuse(0, 16);  diffuse(1, 128); diffuse(2, 160); }
      else        { diffuse(3, 192); diffuse(4, 224); }
      SYNC();                                            // BAR2
      ffrag u0s[2][2], rh[2][2];
      {
        ffrag ga[2][4] = {{fz, fz, fz, fz}, {fz, fz, fz, fz}};
        gate4<8>(ga, bw16, arow0, arow1, bpg, lq);
#pragma unroll
        for (int i = 0; i < 2; ++i)
#pragma unroll
          for (int j = 0; j < 2; ++j)
#pragma unroll
            for (int r = 0; r < 4; ++r) {
              float rr = sigm(ga[i][j][r] + bgr[j]);
              rh[i][j][r]  = rr * h0m[i][j][r];
              u0s[i][j][r] = sigm(ga[i][2+j][r] + bgu[j]);
            }
      }
      // rh dm0 double-buffered -> cols 256-319 (no gate WAR); difT rows 16-79
      // were last read pre-BAR2 (diffuse1) -> safe to overwrite now.
      dumpCell(rh, 256, 16);
      prebC8(bw8, bpc);
      SYNC();                                            // BAR3
      if (e == 0) { diffuse(1, 128); diffuse(2, 160); }  // rh dm12 overwrite
      else        { diffuse(3, 192); diffuse(4, 224); }
      SYNC();                                            // BAR4
      {
        ffrag ca[2][2] = {{fz, fz}, {fz, fz}};
        cand2<8>(ca, bw8, arow0, arow1, kofs0, bpc, lq);
#pragma unroll
        for (int i = 0; i < 2; ++i)
#pragma unroll
          for (int j = 0; j < 2; ++j)
#pragma unroll
            for (int r = 0; r < 4; ++r) {
              float cc = tanh_(ca[i][j][r] + bcv[j]);
              float uu = u0s[i][j][r];
              h0m[i][j][r] = uu*h0m[i][j][r] + (1.f - uu)*cc;
            }
      }
      if (t >= 8) waitge(cons, t - 7);                   // FIFO backpressure
      { // send h0' ch-major [64 ch][128 nodes]
        unsigned short* slot = wt + FIFO_SLOT(b, t);
#pragma unroll
        for (int i = 0; i < 2; ++i)
#pragma unroll
          for (int j = 0; j < 2; ++j) {
            const int chh = 32*e + 16*j + ln;
            const int n0 = 32*g + 16*i + 4*lq;
            us4 q = {f2b(h0m[i][j][0]), f2b(h0m[i][j][1]),
                     f2b(h0m[i][j][2]), f2b(h0m[i][j][3])};
            *(us4*)&slot[chh*128 + n0] = q;
          }
      }
      // Per-wave publish: each wave drains ITS OWN sends (vmcnt) and releases;
      // B waits for all 8. Avoids the block-wide __syncthreads store-drain.
      asm volatile("s_waitcnt vmcnt(0)" ::: "memory");
      if ((tid & 63) == 0)
        __hip_atomic_fetch_add(prod, 1, __ATOMIC_RELEASE, __HIP_MEMORY_SCOPE_AGENT);
      SYNC();                                            // BAR5: LDS protect only
    }
    return;
  }

  // ===== Block B: L1. cols [h0' dm0 0-63|h0' dm12 64-191|h1 dm0 192-255|h1/rh dm12 256-383|rh dm0 384-447]
  {
    const unsigned short* bpg[4] = {
      wt + WT1G_OFF + (16*(2*e)     + ln)*384, wt + WT1G_OFF + (16*(2*e + 1) + ln)*384,
      wt + WT1G_OFF + (16*(4 + 2*e) + ln)*384, wt + WT1G_OFF + (16*(5 + 2*e) + ln)*384 };
    const unsigned short* bpc[2] = {
      wt + WT1C_OFF + (16*(2*e) + ln)*384, wt + WT1C_OFF + (16*(2*e + 1) + ln)*384 };
    const float bgr[2] = { b1g[32*e + ln], b1g[32*e + 16 + ln] };
    const float bgu[2] = { b1g[64 + 32*e + ln], b1g[64 + 32*e + 16 + ln] };
    const float bcv[2] = { b1c[32*e + ln], b1c[32*e + 16 + ln] };
    const int kofs1[12] = {0, 32, 64, 96, 128, 160, 256, 288, 320, 352, 384, 416};
    ffrag h1m[2][2] = {{fz, fz}, {fz, fz}};

#pragma clang loop unroll(disable)
    for (int t = 0; t < L; ++t) {
      waitge(prod, 8*(t + 1));                   // all 8 A-waves published step t
      { // P1: recv h0'(t) -> difT rows 0-63 + diffb cols 0-63; dump h1 (192 / 64)
        const unsigned short* slot = wt + FIFO_SLOT(b, t);
#pragma unroll
        for (int rep = 0; rep < 4; ++rep) {
          const int idx = tid + 512*rep;             // u64 index in 16KB slot
          const int ch = idx >> 5, n0 = (idx & 31)*4;
          ull v = __hip_atomic_load((const ull*)&slot[ch*128 + n0],
                                    __ATOMIC_RELAXED, __HIP_MEMORY_SCOPE_AGENT);
          *(ull*)&difT[ch*PT + n0] = v;
          union { ull u; unsigned short s[4]; } cv; cv.u = v;
#pragma unroll
          for (int j = 0; j < 4; ++j) diffb[(n0 + j)*PD + ch] = cv.s[j];
        }
        dumpCell(h1m, 192, 64);
        prebG16(bw16, bpg);
      }
      SYNC();                                            // BAR1
      if (tid == 0)
        __hip_atomic_fetch_add(cons, 1, __ATOMIC_RELEASE, __HIP_MEMORY_SCOPE_AGENT);
      if (e == 0) { diffuse(0, 64);  diffuse(1, 96);  diffuse(2, 128); diffuse(3, 160); }
      else        { diffuse(4, 256); diffuse(5, 288); diffuse(6, 320); diffuse(7, 352); }
      SYNC();                                            // BAR2
      ffrag u1s[2][2], rh[2][2];
      {
        ffrag ga[2][4] = {{fz, fz, fz, fz}, {fz, fz, fz, fz}};
        gate4<12>(ga, bw16, arow0, arow1, bpg, lq);
#pragma unroll
        for (int i = 0; i < 2; ++i)
#pragma unroll
          for (int j = 0; j < 2; ++j)
#pragma unroll
            for (int r = 0; r < 4; ++r) {
              float rr = sigm(ga[i][j][r] + bgr[j]);
              rh[i][j][r]  = rr * h1m[i][j][r];
              u1s[i][j][r] = sigm(ga[i][2+j][r] + bgu[j]);
            }
      }
      dumpCell(rh, 384, 64);     // rh dm0 -> fresh cols; difT rows 64-127 safe post-BAR2
      prebC8(bw8, bpc);
      SYNC();                                            // BAR3
      if (e == 0) { diffuse(4, 256); diffuse(5, 288); }  // rh dm12 overwrite
      else        { diffuse(6, 320); diffuse(7, 352); }
      SYNC();                                            // BAR4
      {
        ffrag ca[2][2] = {{fz, fz}, {fz, fz}};
        cand2<12>(ca, bw8, arow0, arow1, kofs1, bpc, lq);
#pragma unroll
        for (int i = 0; i < 2; ++i)
#pragma unroll
          for (int j = 0; j < 2; ++j)
#pragma unroll
            for (int r = 0; r < 4; ++r) {
              float cc = tanh_(ca[i][j][r] + bcv[j]);
              float uu = u1s[i][j][r];
              h1m[i][j][r] = uu*h1m[i][j][r] + (1.f - uu)*cc;
            }
      }
      SYNC();                                            // BAR5 (cand reads done)
    }

    // Head: relu(h1) @ W_fc + b_fc, max over nodes
    {
      float* hb = (float*)lds;                  // [128][64]
#pragma unroll
      for (int i = 0; i < 2; ++i)
#pragma unroll
        for (int j = 0; j < 2; ++j)
#pragma unroll
          for (int r = 0; r < 4; ++r) {
            float v = h1m[i][j][r];
            hb[(32*g + 16*i + 4*lq + r)*U_ + 32*e + 16*j + ln] = v > 0.f ? v : 0.f;
          }
    }
    __syncthreads();
    float* hb = (float*)lds;
    float* lb = hb + N_*U_;
    if (tid < N_) {
      float lg[4];
#pragma unroll
      for (int j = 0; j < 4; ++j) lg[j] = bfc[j];
      for (int ch = 0; ch < U_; ++ch) {
        float v = hb[tid*U_ + ch];
#pragma unroll
        for (int j = 0; j < 4; ++j) lg[j] += v * wfc[ch*4 + j];
      }
#pragma unroll
      for (int j = 0; j < 4; ++j) lb[tid*4 + j] = lg[j];
    }
    __syncthreads();
    if (tid < 4) {
      float m = lb[tid];
      for (int n = 1; n < N_; ++n) m = fmaxf(m, lb[n*4 + tid]);
      out[b*4 + tid] = m;
    }
  }
}

extern "C" void kernel_launch(void* const* d_in, const int* in_sizes, int n_in,
                              void* d_out, int out_size, void* d_ws, size_t ws_size,
                              hipStream_t stream) {
  const float* xseq = (const float*)d_in[0];
  const int*   slen = (const int*)  d_in[1];
  const float* sup  = (const float*)d_in[2];
  const float* w0g  = (const float*)d_in[3];
  const float* b0g  = (const float*)d_in[4];
  const float* w0c  = (const float*)d_in[5];
  const float* b0c  = (const float*)d_in[6];
  const float* w1g  = (const float*)d_in[7];
  const float* b1g  = (const float*)d_in[8];
  const float* w1c  = (const float*)d_in[9];
  const float* b1c  = (const float*)d_in[10];
  const float* wfc  = (const float*)d_in[11];
  const float* bfc  = (const float*)d_in[12];
  float* out = (float*)d_out;
  unsigned short* wt = (unsigned short*)d_ws;

  (void)hipFuncSetAttribute((const void*)dcgru,
                            hipFuncAttributeMaxDynamicSharedMemorySize, LDS_BYTES);
  zero_flags<<<dim3(1), dim3(64), 0, stream>>>(wt);
  setup_wt<<<dim3((WT_TOTAL + 255)/256), dim3(256), 0, stream>>>(w0g, w0c, w1g, w1c, wt);
  setup_s2<<<dim3(64), dim3(256), 0, stream>>>(sup, wt + S2_OFF);
  dcgru<<<dim3(64), dim3(512), LDS_BYTES, stream>>>(
      xseq, slen, sup, b0g, b0c, b1g, b1c, wfc, bfc, wt, out);
}

// Round 12
// 2593.751 us; speedup vs baseline: 2.2491x; 1.9195x over previous
//
#include <hip/hip_runtime.h>

// Problem constants
#define B_   32
#define T_   256
#define N_   128
#define DIN_ 16
#define U_   64

// LDS (ushort): diffb [128 nodes][PD] node-major; difT [128 ch][PT] ch-major
#define PD 456
#define PT 136
#define LDS_BYTES ((N_*PD + N_*PT)*2)   // 151552 B

// Workspace (ushort elems)
#define WT0G_OFF 0
#define WT0C_OFF (128*256)
#define WT1G_OFF (WT0C_OFF + 64*256)
#define WT1C_OFF (WT1G_OFF + 128*384)
#define WT_TOTAL (WT1C_OFF + 64*384)
#define S2_OFF   WT_TOTAL                 // bf16 S2[128][128]
#define FIFO_OFF (S2_OFF + 128*128)       // h0' stream: [b][t%8] x 8192 ush (16KB)
#define FIFO_SLOT(bb,tt) (FIFO_OFF + ((bb)*8 + ((tt)&7))*8192)
#define FLG_BYTE ((FIFO_OFF + 32*8*8192)*2)  // int prod[32]; int cons[32]

typedef __attribute__((ext_vector_type(8))) short bfrag;
typedef __attribute__((ext_vector_type(4))) float ffrag;
typedef __attribute__((ext_vector_type(4))) unsigned short us4;
typedef __attribute__((ext_vector_type(2))) unsigned short us2;
typedef unsigned long long ull;

// LDS-only barrier (no vmcnt drain)
#define SYNC() asm volatile("s_waitcnt lgkmcnt(0)\n\ts_barrier" ::: "memory")
#define MFMA16(a,b,c) __builtin_amdgcn_mfma_f32_16x16x32_bf16(a,b,c,0,0,0)

__device__ __forceinline__ unsigned short f2b(float x) {
  union { float f; unsigned u; } v; v.f = x;
  return (unsigned short)((v.u + 0x7fffu + ((v.u >> 16) & 1u)) >> 16);
}
__device__ __forceinline__ float sigm(float x) {
  float e = __expf(-x);
  return __builtin_amdgcn_rcpf(1.f + e);
}
__device__ __forceinline__ float tanh_(float x) {
  float e = __expf(2.f * x);
  return 1.f - 2.f * __builtin_amdgcn_rcpf(1.f + e);
}

// L0 gate k-map (K=256): [x dm0 16 | x dm12 32 | zero 16 | h dm0 64 | h dm12 128]
__device__ __forceinline__ float wval0(const float* w, int ncol, int co, int k) {
  if (k < 16)  return w[(k*3+0)*ncol+co] - w[(k*3+2)*ncol+co];
  if (k < 48)  { int j=k-16, c=j>>1;
                 return (j&1) ? 2.f*w[(c*3+2)*ncol+co] : w[(c*3+1)*ncol+co]; }
  if (k < 64)  return 0.f;
  if (k < 128) { int c=16+(k-64); return w[(c*3+0)*ncol+co] - w[(c*3+2)*ncol+co]; }
  { int j=k-128, c=16+(j>>1);
    return (j&1) ? 2.f*w[(c*3+2)*ncol+co] : w[(c*3+1)*ncol+co]; }
}
// L1 gate k-map (K=384): [h0' dm0 64 | h0' dm12 128 | h1 dm0 64 | h1 dm12 128]
__device__ __forceinline__ float wval1(const float* w, int ncol, int co, int k) {
  if (k < 64)  return w[(k*3+0)*ncol+co] - w[(k*3+2)*ncol+co];
  if (k < 192) { int j=k-64, c=j>>1;
                 return (j&1) ? 2.f*w[(c*3+2)*ncol+co] : w[(c*3+1)*ncol+co]; }
  if (k < 256) { int c=64+(k-192); return w[(c*3+0)*ncol+co] - w[(c*3+2)*ncol+co]; }
  { int j=k-256, c=64+(j>>1);
    return (j&1) ? 2.f*w[(c*3+2)*ncol+co] : w[(c*3+1)*ncol+co]; }
}
// cand k-orders (rh double-buffered):
// L0 cand cols: [x/zero 0-63 | rh dm12 @128-255 | rh dm0 @256-319]
__device__ __forceinline__ float wval0c(const float* w, int ncol, int co, int k) {
  if (k < 64)  return wval0(w, ncol, co, k);
  if (k < 192) return wval0(w, ncol, co, k + 64);
  return wval0(w, ncol, co, k - 128);
}
// L1 cand cols: [h0' 0-191 | rh dm12 @256-383 | rh dm0 @384-447]
__device__ __forceinline__ float wval1c(const float* w, int ncol, int co, int k) {
  if (k < 192) return wval1(w, ncol, co, k);
  if (k < 320) return wval1(w, ncol, co, k + 64);
  return wval1(w, ncol, co, k - 128);
}

__global__ void setup_wt(const float* __restrict__ w0g, const float* __restrict__ w0c,
                         const float* __restrict__ w1g, const float* __restrict__ w1c,
                         unsigned short* __restrict__ wt) {
  int i = blockIdx.x * blockDim.x + threadIdx.x;
  if (i >= WT_TOTAL) return;
  float v;
  if (i < WT0C_OFF)      { int co = i >> 8, k = i & 255;                 v = wval0 (w0g, 128, co, k); }
  else if (i < WT1G_OFF) { int j = i - WT0C_OFF; v = wval0c(w0c, 64, j >> 8, j & 255); }
  else if (i < WT1C_OFF) { int j = i - WT1G_OFF; v = wval1 (w1g, 128, j / 384, j % 384); }
  else                   { int j = i - WT1C_OFF; v = wval1c(w1c, 64, j / 384, j % 384); }
  wt[i] = f2b(v);
}

__global__ void setup_s2(const float* __restrict__ sup, unsigned short* __restrict__ s2) {
  int idx = blockIdx.x * blockDim.x + threadIdx.x;
  int i = idx >> 7, j = idx & 127;
  float acc = 0.f;
#pragma unroll 4
  for (int k = 0; k < 128; ++k) acc += sup[i*128 + k] * sup[k*128 + j];
  s2[idx] = f2b(acc);
}

__global__ void zero_flags(unsigned short* __restrict__ wt) {
  int* flg = (int*)((char*)wt + FLG_BYTE);
  if (threadIdx.x < 64) flg[threadIdx.x] = 0;
}

// Gate GEMM, REGISTER-RESIDENT weights: 4 m-tiles x {r,u}; zero vm ops in loop.
template<int KT>
__device__ __forceinline__ void gateR(ffrag (&acc)[4][2],
    const bfrag (&bwr)[KT], const bfrag (&bwu)[KT],
    const unsigned short* __restrict__ arowB, const int lq) {
#pragma unroll
  for (int ks = 0; ks < KT; ++ks) {
    bfrag a[4];
#pragma unroll
    for (int i = 0; i < 4; ++i)
      a[i] = *(const bfrag*)&arowB[16*i*PD + 32*ks + 8*lq];
#pragma unroll
    for (int i = 0; i < 4; ++i) {
      acc[i][0] = MFMA16(a[i], bwr[ks], acc[i][0]);
      acc[i][1] = MFMA16(a[i], bwu[ks], acc[i][1]);
    }
  }
}
// Cand GEMM: 4 m-tiles x 1 co; A-cols via ks-offset list; 4-deep streamed ring.
template<int KT>
__device__ __forceinline__ void candR(ffrag (&acc)[4], bfrag (&bw)[4],
    const unsigned short* __restrict__ arowB, const int (&kofs)[KT],
    const unsigned short* __restrict__ bpc, const int lq) {
#pragma unroll
  for (int ks = 0; ks < KT; ++ks) {
    const int k = ks & 3;
    bfrag a[4];
#pragma unroll
    for (int i = 0; i < 4; ++i)
      a[i] = *(const bfrag*)&arowB[16*i*PD + kofs[ks] + 8*lq];
    bfrag bc = bw[k];
    if (ks + 4 < KT) bw[k] = *(const bfrag*)&bpc[32*(ks+4) + 8*lq];
#pragma unroll
    for (int i = 0; i < 4; ++i) acc[i] = MFMA16(a[i], bc, acc[i]);
  }
}

__global__ __launch_bounds__(512, 2) void dcgru(
    const float* __restrict__ xseq, const int* __restrict__ slen,
    const float* __restrict__ sup,
    const float* __restrict__ b0g, const float* __restrict__ b0c,
    const float* __restrict__ b1g, const float* __restrict__ b1c,
    const float* __restrict__ wfc, const float* __restrict__ bfc,
    unsigned short* __restrict__ wt, float* __restrict__ out) {
  extern __shared__ unsigned short lds[];
  unsigned short* diffb = lds;
  unsigned short* difT  = lds + N_*PD;
  // XCD-local A/B pairing (A=x, B=x+8 share XCD under round-robin dispatch)
  const int b    = (blockIdx.x & 7) | ((blockIdx.x >> 4) << 3);
  const int eta  = (blockIdx.x >> 3) & 1;
  const int tid  = threadIdx.x;
  const int w    = tid >> 6;              // wave 0..7
  const int j    = w & 3;                 // ch-tile: ch [16j, 16j+16)
  const int g    = w >> 2;                // node-half: m-tiles 4g..4g+3 (64 nodes)
  const int ln   = tid & 15;
  const int lq   = (tid >> 4) & 3;
  const int L    = slen[b];
  int* flg  = (int*)((char*)wt + FLG_BYTE);
  int* prod = flg + b;
  int* cons = flg + 32 + b;
  const unsigned short* __restrict__ arowB = diffb + (64*g + ln)*PD;
  const ffrag fz = {0.f, 0.f, 0.f, 0.f};

  // S / S2 A-frags for diffuse strip w (1 strip, 8 bfrags = 32 VGPR)
  bfrag Sf[4], S2f[4];
#pragma unroll
  for (int ks = 0; ks < 4; ++ks) {
    const float* pS = sup + (16*w + ln)*N_ + 32*ks + 8*lq;
    union { bfrag v; unsigned short u[8]; } tmp;
#pragma unroll
    for (int jj = 0; jj < 8; ++jj) tmp.u[jj] = f2b(pS[jj]);
    Sf[ks] = tmp.v;
    S2f[ks] = *(const bfrag*)&wt[S2_OFF + (16*w + ln)*N_ + 32*ks + 8*lq];
  }

  // diffuse ch-tile nt for strip w: dm1=S@xc, dm2=S2@xc; cols colc + 2*ln + {0,1}
  auto diffuse = [&](int nt, int colc) {
    bfrag bf[4];
#pragma unroll
    for (int ks = 0; ks < 4; ++ks)
      bf[ks] = *(const bfrag*)&difT[(16*nt + ln)*PT + 32*ks + 8*lq];
    ffrag a1 = fz, a2 = fz;
#pragma unroll
    for (int ks = 0; ks < 4; ++ks) {
      a1 = MFMA16(Sf[ks],  bf[ks], a1);
      a2 = MFMA16(S2f[ks], bf[ks], a2);
    }
    const int n0 = 16*w + 4*lq;
    const int col = colc + 2*ln;
#pragma unroll
    for (int r = 0; r < 4; ++r) {
      us2 pq = {f2b(a1[r]), f2b(a2[r])};
      *(us2*)&diffb[(n0 + r)*PD + col] = pq;
    }
  };
  // dump wave's 4m x 1ch C-frags into both layouts
  auto dumpCell = [&](ffrag (&v)[4], int colBase, int rowBase) {
    const int chh = 16*j + ln;
#pragma unroll
    for (int i = 0; i < 4; ++i) {
      const int n0 = 64*g + 16*i + 4*lq;
      unsigned short sv[4];
#pragma unroll
      for (int r = 0; r < 4; ++r) sv[r] = f2b(v[i][r]);
#pragma unroll
      for (int r = 0; r < 4; ++r) diffb[(n0 + r)*PD + colBase + chh] = sv[r];
      us4 q = {sv[0], sv[1], sv[2], sv[3]};
      *(us4*)&difT[(rowBase + chh)*PT + n0] = q;
    }
  };
  auto prebC = [&](bfrag (&bw)[4], const unsigned short* bpc) {
#pragma unroll
    for (int k = 0; k < 4; ++k) bw[k] = *(const bfrag*)&bpc[32*k + 8*lq];
  };
  auto waitge = [&](int* p, int seq) {
    if ((tid & 63) == 0) {
      int it = 0;
      while (__hip_atomic_load(p, __ATOMIC_RELAXED, __HIP_MEMORY_SCOPE_AGENT) < seq) {
        __builtin_amdgcn_s_sleep(1);
        if (++it > (1 << 24)) break;            // failsafe: never hard-hang
      }
    }
  };

  bfrag bw4[4];

  if (eta == 0) {
    // ===== Block A: L0. cols [x 0-15|x dm12 16-47|z 48-63|h dm0 64-127|h dm12 128-255|rh dm0 256-319]
    // Resident gate weights: r_j, u_j, K=256 (16 bfrags = 64 VGPR)
    bfrag bwr[8], bwu[8];
    {
      const unsigned short* bpr = wt + WT0G_OFF + (16*j      + ln)*256;
      const unsigned short* bpu = wt + WT0G_OFF + (16*(4+j)  + ln)*256;
#pragma unroll
      for (int ks = 0; ks < 8; ++ks) {
        bwr[ks] = *(const bfrag*)&bpr[32*ks + 8*lq];
        bwu[ks] = *(const bfrag*)&bpu[32*ks + 8*lq];
      }
    }
    const unsigned short* bpc = wt + WT0C_OFF + (16*j + ln)*256;
    const float bgr = b0g[16*j + ln], bgu = b0g[64 + 16*j + ln];
    const float bcv = b0c[16*j + ln];
    const int kofs0[8] = {0, 32, 128, 160, 192, 224, 256, 288};
    ffrag h0m[4] = {fz, fz, fz, fz};

    for (int i = tid; i < N_*16; i += 512)     // zero pad cols [48,64) once
      diffb[(i >> 4)*PD + 48 + (i & 15)] = 0;
    float4 xv = *(const float4*)&xseq[(size_t)(b*T_)*N_*DIN_ + 4*tid];

#pragma clang loop unroll(disable)
    for (int t = 0; t < L; ++t) {
      { // P1: stage x (cols 0-15 / difT rows 0-15); dump h0 (cols 64-127 / rows 16-79)
        const int node = tid >> 2, c = 4*(tid & 3);
        unsigned short s0 = f2b(xv.x), s1 = f2b(xv.y), s2 = f2b(xv.z), s3 = f2b(xv.w);
        us4 q = {s0, s1, s2, s3};
        *(us4*)&diffb[node*PD + c] = q;
        difT[(c+0)*PT + node] = s0; difT[(c+1)*PT + node] = s1;
        difT[(c+2)*PT + node] = s2; difT[(c+3)*PT + node] = s3;
        dumpCell(h0m, 64, 16);
        int tn = t + 1 < L ? t + 1 : L - 1;
        xv = *(const float4*)&xseq[(size_t)(b*T_ + tn)*N_*DIN_ + 4*tid];
      }
      SYNC();                                            // BAR1
      diffuse(0, 16);  diffuse(1, 128); diffuse(2, 160);
      diffuse(3, 192); diffuse(4, 224);
      SYNC();                                            // BAR2
      ffrag u0s[4], rh[4];
      {
        ffrag ga[4][2] = {{fz, fz}, {fz, fz}, {fz, fz}, {fz, fz}};
        gateR<8>(ga, bwr, bwu, arowB, lq);
#pragma unroll
        for (int i = 0; i < 4; ++i)
#pragma unroll
          for (int r = 0; r < 4; ++r) {
            float rr = sigm(ga[i][0][r] + bgr);
            rh[i][r]  = rr * h0m[i][r];
            u0s[i][r] = sigm(ga[i][1][r] + bgu);
          }
      }
      dumpCell(rh, 256, 16);                 // rh dm0 -> fresh cols (no gate WAR)
      prebC(bw4, bpc);
      SYNC();                                            // BAR3
      diffuse(1, 128); diffuse(2, 160); diffuse(3, 192); diffuse(4, 224);
      SYNC();                                            // BAR4
      {
        ffrag ca[4] = {fz, fz, fz, fz};
        candR<8>(ca, bw4, arowB, kofs0, bpc, lq);
#pragma unroll
        for (int i = 0; i < 4; ++i)
#pragma unroll
          for (int r = 0; r < 4; ++r) {
            float cc = tanh_(ca[i][r] + bcv);
            float uu = u0s[i][r];
            h0m[i][r] = uu*h0m[i][r] + (1.f - uu)*cc;
          }
      }
      if (t >= 8) waitge(cons, t - 7);                   // FIFO backpressure
      { // send h0' ch-major [64 ch][128 nodes]
        unsigned short* slot = wt + FIFO_SLOT(b, t);
        const int chh = 16*j + ln;
#pragma unroll
        for (int i = 0; i < 4; ++i) {
          const int n0 = 64*g + 16*i + 4*lq;
          us4 q = {f2b(h0m[i][0]), f2b(h0m[i][1]), f2b(h0m[i][2]), f2b(h0m[i][3])};
          *(us4*)&slot[chh*128 + n0] = q;
        }
      }
      asm volatile("s_waitcnt vmcnt(0)" ::: "memory");    // drain own sends
      if ((tid & 63) == 0)
        __hip_atomic_fetch_add(prod, 1, __ATOMIC_RELEASE, __HIP_MEMORY_SCOPE_AGENT);
      SYNC();                                            // BAR5: LDS protect only
    }
    return;
  }

  // ===== Block B: L1. cols [h0' dm0 0-63|h0' dm12 64-191|h1 dm0 192-255|h1/rh dm12 256-383|rh dm0 384-447]
  {
    // Resident gate weights: r_j, u_j, K=384 (24 bfrags = 96 VGPR)
    bfrag bwr[12], bwu[12];
    {
      const unsigned short* bpr = wt + WT1G_OFF + (16*j     + ln)*384;
      const unsigned short* bpu = wt + WT1G_OFF + (16*(4+j) + ln)*384;
#pragma unroll
      for (int ks = 0; ks < 12; ++ks) {
        bwr[ks] = *(const bfrag*)&bpr[32*ks + 8*lq];
        bwu[ks] = *(const bfrag*)&bpu[32*ks + 8*lq];
      }
    }
    const unsigned short* bpc = wt + WT1C_OFF + (16*j + ln)*384;
    const float bgr = b1g[16*j + ln], bgu = b1g[64 + 16*j + ln];
    const float bcv = b1c[16*j + ln];
    const int kofs1[12] = {0, 32, 64, 96, 128, 160, 256, 288, 320, 352, 384, 416};
    ffrag h1m[4] = {fz, fz, fz, fz};

#pragma clang loop unroll(disable)
    for (int t = 0; t < L; ++t) {
      waitge(prod, 8*(t + 1));                 // all 8 A-waves published step t
      { // P1: recv h0'(t) -> difT rows 0-63 + diffb cols 0-63; dump h1 (192 / 64)
        const unsigned short* slot = wt + FIFO_SLOT(b, t);
#pragma unroll
        for (int rep = 0; rep < 4; ++rep) {
          const int idx = tid + 512*rep;
          const int ch = idx >> 5, n0 = (idx & 31)*4;
          ull v = __hip_atomic_load((const ull*)&slot[ch*128 + n0],
                                    __ATOMIC_RELAXED, __HIP_MEMORY_SCOPE_AGENT);
          *(ull*)&difT[ch*PT + n0] = v;
          union { ull u; unsigned short s[4]; } cv; cv.u = v;
#pragma unroll
          for (int jj = 0; jj < 4; ++jj) diffb[(n0 + jj)*PD + ch] = cv.s[jj];
        }
        dumpCell(h1m, 192, 64);
      }
      SYNC();                                            // BAR1
      if (tid == 0)
        __hip_atomic_fetch_add(cons, 1, __ATOMIC_RELEASE, __HIP_MEMORY_SCOPE_AGENT);
      diffuse(0, 64);  diffuse(1, 96);  diffuse(2, 128); diffuse(3, 160);
      diffuse(4, 256); diffuse(5, 288); diffuse(6, 320); diffuse(7, 352);
      SYNC();                                            // BAR2
      ffrag u1s[4], rh[4];
      {
        ffrag ga[4][2] = {{fz, fz}, {fz, fz}, {fz, fz}, {fz, fz}};
        gateR<12>(ga, bwr, bwu, arowB, lq);
#pragma unroll
        for (int i = 0; i < 4; ++i)
#pragma unroll
          for (int r = 0; r < 4; ++r) {
            float rr = sigm(ga[i][0][r] + bgr);
            rh[i][r]  = rr * h1m[i][r];
            u1s[i][r] = sigm(ga[i][1][r] + bgu);
          }
      }
      dumpCell(rh, 384, 64);                 // rh dm0 -> fresh cols
      prebC(bw4, bpc);
      SYNC();                                            // BAR3
      diffuse(4, 256); diffuse(5, 288); diffuse(6, 320); diffuse(7, 352);
      SYNC();                                            // BAR4
      {
        ffrag ca[4] = {fz, fz, fz, fz};
        candR<12>(ca, bw4, arowB, kofs1, bpc, lq);
#pragma unroll
        for (int i = 0; i < 4; ++i)
#pragma unroll
          for (int r = 0; r < 4; ++r) {
            float cc = tanh_(ca[i][r] + bcv);
            float uu = u1s[i][r];
            h1m[i][r] = uu*h1m[i][r] + (1.f - uu)*cc;
          }
      }
      SYNC();                                            // BAR5 (cand reads done)
    }

    // Head: relu(h1) @ W_fc + b_fc, max over nodes
    {
      float* hb = (float*)lds;                  // [128][64]
#pragma unroll
      for (int i = 0; i < 4; ++i)
#pragma unroll
        for (int r = 0; r < 4; ++r) {
          float v = h1m[i][r];
          hb[(64*g + 16*i + 4*lq + r)*U_ + 16*j + ln] = v > 0.f ? v : 0.f;
        }
    }
    __syncthreads();
    float* hb = (float*)lds;
    float* lb = hb + N_*U_;
    if (tid < N_) {
      float lg[4];
#pragma unroll
      for (int jj = 0; jj < 4; ++jj) lg[jj] = bfc[jj];
      for (int ch = 0; ch < U_; ++ch) {
        float v = hb[tid*U_ + ch];
#pragma unroll
        for (int jj = 0; jj < 4; ++jj) lg[jj] += v * wfc[ch*4 + jj];
      }
#pragma unroll
      for (int jj = 0; jj < 4; ++jj) lb[tid*4 + jj] = lg[jj];
    }
    __syncthreads();
    if (tid < 4) {
      float m = lb[tid];
      for (int n = 1; n < N_; ++n) m = fmaxf(m, lb[n*4 + tid]);
      out[b*4 + tid] = m;
    }
  }
}

extern "C" void kernel_launch(void* const* d_in, const int* in_sizes, int n_in,
                              void* d_out, int out_size, void* d_ws, size_t ws_size,
                              hipStream_t stream) {
  const float* xseq = (const float*)d_in[0];
  const int*   slen = (const int*)  d_in[1];
  const float* sup  = (const float*)d_in[2];
  const float* w0g  = (const float*)d_in[3];
  const float* b0g  = (const float*)d_in[4];
  const float* w0c  = (const float*)d_in[5];
  const float* b0c  = (const float*)d_in[6];
  const float* w1g  = (const float*)d_in[7];
  const float* b1g  = (const float*)d_in[8];
  const float* w1c  = (const float*)d_in[9];
  const float* b1c  = (const float*)d_in[10];
  const float* wfc  = (const float*)d_in[11];
  const float* bfc  = (const float*)d_in[12];
  float* out = (float*)d_out;
  unsigned short* wt = (unsigned short*)d_ws;

  (void)hipFuncSetAttribute((const void*)dcgru,
                            hipFuncAttributeMaxDynamicSharedMemorySize, LDS_BYTES);
  zero_flags<<<dim3(1), dim3(64), 0, stream>>>(wt);
  setup_wt<<<dim3((WT_TOTAL + 255)/256), dim3(256), 0, stream>>>(w0g, w0c, w1g, w1c, wt);
  setup_s2<<<dim3(64), dim3(256), 0, stream>>>(sup, wt + S2_OFF);
  dcgru<<<dim3(64), dim3(512), LDS_BYTES, stream>>>(
      xseq, slen, sup, b0g, b0c, b1g, b1c, wfc, bfc, wt, out);
}